// Round 1
// baseline (233.195 us; speedup 1.0000x reference)
//
#include <hip/hip_runtime.h>

// GraphAttentionLayer: B=1, N=4096, F=256, H=8, U=64
//
// Key identity: e_src cancels in softmax over j =>
//   alpha[i,j,h] = A[i,j] * exp(e_dst[j,h]) / sum_j A[i,j]*exp(e_dst[j,h])
//   out[i, u*8+h] = relu( num[i,h,u] / den[i,h] )
//   num = A @ (w*h), den = A @ w   -> ONE dense GEMM  A(4096x4096) x G(4096x640)
// G columns: [0,512): w[j,h]*h[j,h,u] at col h*64+u ; [512,520): w[j,h] ; [520,640): 0
//
// ws layout (bytes):
//   Abf  @ 0         : 4096*4096*2  = 33554432   (A in bf16, exact since A in {0,1})
//   Gt   @ 33554432  : 640*4096*2   = 5242880    (G transposed: Gt[n][k], k contiguous)
//   ht   @ 38797312  : 512*4096*4   = 8388608    (h transposed: ht[c][j])
//   ed   @ 47185920  : 4096*8*4     = 131072     (e_dst[j][h])
//   w8   @ 47316992  : 8*4096*4     = 131072     (w[h][j] = exp(e_dst))
//   P    @ 47448064  : 4*4096*640*4 = 41943040   (split-K partials)
//   total ~85.3 MiB

typedef unsigned short u16;
typedef unsigned int   u32;
typedef __attribute__((ext_vector_type(8))) short  short8;   // 8 x bf16 (4 VGPRs)
typedef __attribute__((ext_vector_type(4))) float  floatx4;  // MFMA acc
typedef __attribute__((ext_vector_type(4))) unsigned short u16x4;

__device__ __forceinline__ u16 f2bf(float x) {
  u32 u = __float_as_uint(x);
  u += 0x7fffu + ((u >> 16) & 1u);   // round-to-nearest-even
  return (u16)(u >> 16);
}

__device__ __forceinline__ void async_ld16(const void* g, void* l) {
  __builtin_amdgcn_global_load_lds((const __attribute__((address_space(1))) void*)g,
                                   (__attribute__((address_space(3))) void*)l,
                                   16, 0, 0);
}

// ---------------------------------------------------------------------------
// Kernel 1: h = X @ W (fp32), fused e_dst[j][h] = sum_u h[j,h,u]*a[64+u].
// Writes ht[c][j] (transposed) and ed[j][h]. 16 rows per block, 2 cols/thread.
// ---------------------------------------------------------------------------
__global__ __launch_bounds__(256) void k_xw(const float* __restrict__ X,
                                            const float* __restrict__ W,
                                            const float* __restrict__ av,
                                            float* __restrict__ ht,
                                            float* __restrict__ ed) {
  __shared__ __align__(16) float xs[16 * 256];
  __shared__ float ered[16 * 8];
  const int t  = threadIdx.x;
  const int j0 = blockIdx.x * 16;

  // stage 16 rows of X (coalesced float4)
  const float4* Xv  = (const float4*)(X + (size_t)j0 * 256);
  float4*       xsv = (float4*)xs;
#pragma unroll
  for (int p = 0; p < 4; ++p) xsv[p * 256 + t] = Xv[p * 256 + t];
  if (t < 128) ered[t] = 0.f;
  __syncthreads();

  const int c0 = 2 * t;           // this thread's two W columns: c0, c0+1
  float acc0[16], acc1[16];
#pragma unroll
  for (int r = 0; r < 16; ++r) { acc0[r] = 0.f; acc1[r] = 0.f; }

  for (int kc = 0; kc < 64; ++kc) {           // k in chunks of 4
    float2 w0 = ((const float2*)(W + (size_t)(kc * 4 + 0) * 512))[t];
    float2 w1 = ((const float2*)(W + (size_t)(kc * 4 + 1) * 512))[t];
    float2 w2 = ((const float2*)(W + (size_t)(kc * 4 + 2) * 512))[t];
    float2 w3 = ((const float2*)(W + (size_t)(kc * 4 + 3) * 512))[t];
#pragma unroll
    for (int r = 0; r < 16; ++r) {
      float4 xv = ((const float4*)(xs + r * 256))[kc];   // LDS broadcast
      acc0[r] += xv.x * w0.x + xv.y * w1.x + xv.z * w2.x + xv.w * w3.x;
      acc1[r] += xv.x * w0.y + xv.y * w1.y + xv.z * w2.y + xv.w * w3.y;
    }
  }

  // e_dst partial: both cols are in the same head (c0 even)
  const int   u0  = c0 & 63;
  const int   hd  = c0 >> 6;
  const float as0 = av[64 + u0], as1 = av[64 + u0 + 1];
#pragma unroll
  for (int r = 0; r < 16; ++r)
    atomicAdd(&ered[r * 8 + hd], acc0[r] * as0 + acc1[r] * as1);

  // transposed store: ht[c][j0..j0+15]
  float* h0 = ht + (size_t)c0 * 4096 + j0;
  float* h1 = ht + (size_t)(c0 + 1) * 4096 + j0;
#pragma unroll
  for (int q = 0; q < 4; ++q) {
    float4 v0 = {acc0[4 * q], acc0[4 * q + 1], acc0[4 * q + 2], acc0[4 * q + 3]};
    float4 v1 = {acc1[4 * q], acc1[4 * q + 1], acc1[4 * q + 2], acc1[4 * q + 3]};
    *(float4*)(h0 + q * 4) = v0;
    *(float4*)(h1 + q * 4) = v1;
  }
  __syncthreads();
  if (t < 128) {
    int r = t >> 3, h2 = t & 7;
    ed[(size_t)(j0 + r) * 8 + h2] = ered[t];
  }
}

// ---------------------------------------------------------------------------
// Kernel 2: w8[h][j] = exp(clamp(ed[j][h], -30, 30))
// ---------------------------------------------------------------------------
__global__ __launch_bounds__(256) void k_wexp(const float* __restrict__ ed,
                                              float* __restrict__ w8) {
  int idx = blockIdx.x * 256 + threadIdx.x;   // 0..32767 = hd*4096 + j
  int hd = idx >> 12, j = idx & 4095;
  float e = ed[(size_t)j * 8 + hd];
  e = fminf(30.f, fmaxf(-30.f, e));
  w8[idx] = __expf(e);
}

// ---------------------------------------------------------------------------
// Kernel 3: Gt[c][j] bf16.  c<512: w[c>>6][j]*ht[c][j]; 512<=c<520: w[c-512][j]; else 0
// ---------------------------------------------------------------------------
__global__ __launch_bounds__(256) void k_gt(const float* __restrict__ ht,
                                            const float* __restrict__ w8,
                                            u16* __restrict__ Gt) {
  const int c  = blockIdx.y;
  const int j0 = (blockIdx.x * 256 + threadIdx.x) * 4;
  float4 v;
  if (c < 512) {
    int hd = c >> 6;
    float4 hv = *(const float4*)(ht + (size_t)c * 4096 + j0);
    float4 wv = *(const float4*)(w8 + (size_t)hd * 4096 + j0);
    v.x = hv.x * wv.x; v.y = hv.y * wv.y; v.z = hv.z * wv.z; v.w = hv.w * wv.w;
  } else if (c < 520) {
    v = *(const float4*)(w8 + (size_t)(c - 512) * 4096 + j0);
  } else {
    v.x = v.y = v.z = v.w = 0.f;
  }
  u16x4 o = {f2bf(v.x), f2bf(v.y), f2bf(v.z), f2bf(v.w)};
  *(u16x4*)(Gt + (size_t)c * 4096 + j0) = o;
}

// ---------------------------------------------------------------------------
// Kernel 4: A fp32 -> bf16 (values are exactly 0/1; conversion exact)
// ---------------------------------------------------------------------------
__global__ __launch_bounds__(256) void k_conv(const float* __restrict__ A,
                                              u16* __restrict__ Ab) {
  size_t i = ((size_t)blockIdx.x * 256 + threadIdx.x) * 8;
  float4 a0 = *(const float4*)(A + i);
  float4 a1 = *(const float4*)(A + i + 4);
  uint4 o;
  o.x = (u32)f2bf(a0.x) | ((u32)f2bf(a0.y) << 16);
  o.y = (u32)f2bf(a0.z) | ((u32)f2bf(a0.w) << 16);
  o.z = (u32)f2bf(a1.x) | ((u32)f2bf(a1.y) << 16);
  o.w = (u32)f2bf(a1.z) | ((u32)f2bf(a1.w) << 16);
  *(uint4*)(Ab + i) = o;
}

// ---------------------------------------------------------------------------
// Kernel 5: C = Abf(4096x4096) x Gt^T  -> P[z] (split-K=4 partials, fp32)
// m97 structure: 128x128 tile, BK=32, global_load_lds width 16,
// 4 waves in 2x2, each wave 64x64 = 4x4 MFMA 16x16x32 bf16 tiles.
// ---------------------------------------------------------------------------
__global__ __launch_bounds__(256) void k_gemm(const u16* __restrict__ Ab,
                                              const u16* __restrict__ Gt,
                                              float* __restrict__ P) {
  __shared__ __align__(16) u16 lA[128 * 32];
  __shared__ __align__(16) u16 lB[128 * 32];
  const int t    = threadIdx.x;
  const int n0   = blockIdx.x * 128;
  const int i0   = blockIdx.y * 128;
  const int kt0  = blockIdx.z * 1024;
  const int w    = t >> 6, lane = t & 63;
  const int wr   = w >> 1, wc = w & 1;
  const int quad = lane >> 4, l15 = lane & 15;

  floatx4 acc[4][4];
  const floatx4 zz = {0.f, 0.f, 0.f, 0.f};
#pragma unroll
  for (int mt = 0; mt < 4; ++mt)
#pragma unroll
    for (int nt = 0; nt < 4; ++nt) acc[mt][nt] = zz;

  // staging: element offsets (each thread stages 2x16B per operand tile)
  const int E0 = t * 8;                 // rows 0..63 of the tile
  const int E1 = 2048 + t * 8;          // rows 64..127
  const int r0 = E0 >> 5, kk0 = E0 & 31;
  const int r1 = E1 >> 5, kk1 = E1 & 31;
  const u16* pa0 = Ab + (size_t)(i0 + r0) * 4096 + kt0 + kk0;
  const u16* pa1 = Ab + (size_t)(i0 + r1) * 4096 + kt0 + kk1;
  const u16* pb0 = Gt + (size_t)(n0 + r0) * 4096 + kt0 + kk0;
  const u16* pb1 = Gt + (size_t)(n0 + r1) * 4096 + kt0 + kk1;
  // wave-uniform LDS destinations (HW writes base + lane*16)
  const int wbase = (t & 192) * 8;
  u16* la0 = &lA[wbase];
  u16* la1 = &lA[2048 + wbase];
  u16* lb0 = &lB[wbase];
  u16* lb1 = &lB[2048 + wbase];

  for (int kk = 0; kk < 1024; kk += 32) {
    async_ld16(pa0 + kk, la0);
    async_ld16(pa1 + kk, la1);
    async_ld16(pb0 + kk, lb0);
    async_ld16(pb1 + kk, lb1);
    __syncthreads();   // compiler emits s_waitcnt vmcnt(0) before s_barrier

    short8 af[4], bf[4];
#pragma unroll
    for (int mt = 0; mt < 4; ++mt)
      af[mt] = *(const short8*)&lA[(wr * 64 + mt * 16 + l15) * 32 + quad * 8];
#pragma unroll
    for (int nt = 0; nt < 4; ++nt)
      bf[nt] = *(const short8*)&lB[(wc * 64 + nt * 16 + l15) * 32 + quad * 8];
#pragma unroll
    for (int mt = 0; mt < 4; ++mt)
#pragma unroll
      for (int nt = 0; nt < 4; ++nt)
        acc[mt][nt] = __builtin_amdgcn_mfma_f32_16x16x32_bf16(af[mt], bf[nt],
                                                              acc[mt][nt], 0, 0, 0);
    __syncthreads();
  }

  // epilogue: C/D layout col = lane&15, row = quad*4 + reg
  float* Pp = P + (size_t)blockIdx.z * (4096 * 640);
#pragma unroll
  for (int mt = 0; mt < 4; ++mt) {
#pragma unroll
    for (int r = 0; r < 4; ++r) {
      int i = i0 + wr * 64 + mt * 16 + quad * 4 + r;
      float* row = Pp + (size_t)i * 640 + n0 + wc * 64 + l15;
#pragma unroll
      for (int nt = 0; nt < 4; ++nt) row[nt * 16] = acc[mt][nt][r];
    }
  }
}

// ---------------------------------------------------------------------------
// Kernel 6: out[i, u*8+h] = relu( sum_z P[z][i, h*64+u] / sum_z P[z][i, 512+h] )
// ---------------------------------------------------------------------------
__global__ __launch_bounds__(256) void k_out(const float* __restrict__ P,
                                             float* __restrict__ out) {
  __shared__ float ps[4 * 640];
  const int t = threadIdx.x;
  const int i = blockIdx.x;
#pragma unroll
  for (int z = 0; z < 4; ++z)
    for (int q = t; q < 640; q += 256)
      ps[z * 640 + q] = P[(size_t)z * 2621440 + (size_t)i * 640 + q];
  __syncthreads();
  for (int c = t; c < 512; c += 256) {
    int u = c >> 3, hd = c & 7;
    float num = ps[hd * 64 + u] + ps[640 + hd * 64 + u] +
                ps[1280 + hd * 64 + u] + ps[1920 + hd * 64 + u];
    float den = ps[512 + hd] + ps[640 + 512 + hd] +
                ps[1280 + 512 + hd] + ps[1920 + 512 + hd];
    float o = num / den;
    out[(size_t)i * 512 + c] = fmaxf(o, 0.f);
  }
}

extern "C" void kernel_launch(void* const* d_in, const int* in_sizes, int n_in,
                              void* d_out, int out_size, void* d_ws, size_t ws_size,
                              hipStream_t stream) {
  const float* X  = (const float*)d_in[0];
  const float* A  = (const float*)d_in[1];
  const float* W  = (const float*)d_in[2];
  const float* av = (const float*)d_in[3];
  float* out = (float*)d_out;
  char*  ws  = (char*)d_ws;

  u16*   Ab = (u16*)(ws + 0);
  u16*   Gt = (u16*)(ws + 33554432);
  float* ht = (float*)(ws + 38797312);
  float* ed = (float*)(ws + 47185920);
  float* w8 = (float*)(ws + 47316992);
  float* P  = (float*)(ws + 47448064);

  k_conv<<<8192, 256, 0, stream>>>(A, Ab);
  k_xw<<<256, 256, 0, stream>>>(X, W, av, ht, ed);
  k_wexp<<<128, 256, 0, stream>>>(ed, w8);
  k_gt<<<dim3(4, 640), 256, 0, stream>>>(ht, w8, Gt);
  k_gemm<<<dim3(5, 32, 4), 256, 0, stream>>>(Ab, Gt, P);
  k_out<<<4096, 256, 0, stream>>>(P, out);
}

// Round 2
// 227.487 us; speedup vs baseline: 1.0251x; 1.0251x over previous
//
#include <hip/hip_runtime.h>

// GraphAttentionLayer: B=1, N=4096, F=256, H=8, U=64
//
// e_src cancels in the softmax over j =>
//   out[i, u*8+h] = relu( (A @ (w*h))[i, h*64+u] / (A @ w)[i, h] ),  w = exp(e_dst)
//   e_dst[j,h] = X[j,:] @ Wa[:,h],  Wa[k][h] = sum_u W[k][h*64+u]*a_dst[u]  (tiny)
// => ONE dense GEMM  A(4096x4096) x G(4096x640), G = [w*h | w | 0-pad]
//
// Pipeline (4 kernels):
//   k_conv : A fp32->bf16 (8192 blocks) + 1 extra block computes Wa[256][8]
//   k_hg   : fp32 X@W (16 rows x 128 cols/block, grid 1024 = 4 blk/CU),
//            local e_dst/w, writes Gt[c][j] bf16 directly (+ w rows + zero pad)
//   k_gemm : bf16 MFMA 128x128 tile, BK=32, global_load_lds w16, XOR-swizzled
//            LDS chunks, split-K Z=8 (adaptive; 4 if ws too small)
//   k_out  : sum partials, num/den, relu, (u,h) permute
//
// ws layout: Ab @0 (32MB) | Gt @33554432 (5MB, 640x4096 bf16) |
//            Wa @38797312 (8KB) | P @38805504 (Z x 4096x640 fp32)

typedef unsigned short u16;
typedef unsigned int   u32;
typedef __attribute__((ext_vector_type(8))) short  short8;   // 8 x bf16
typedef __attribute__((ext_vector_type(4))) float  floatx4;  // MFMA acc
typedef __attribute__((ext_vector_type(8))) unsigned short u16x8;

__device__ __forceinline__ u16 f2bf(float x) {
  u32 u = __float_as_uint(x);
  u += 0x7fffu + ((u >> 16) & 1u);   // RNE
  return (u16)(u >> 16);
}

__device__ __forceinline__ void async_ld16(const void* g, void* l) {
  __builtin_amdgcn_global_load_lds((const __attribute__((address_space(1))) void*)g,
                                   (__attribute__((address_space(3))) void*)l,
                                   16, 0, 0);
}

// ---------------------------------------------------------------------------
// Kernel 1: A fp32 -> bf16 (exact: A in {0,1}); block 8192 computes Wa.
// ---------------------------------------------------------------------------
__global__ __launch_bounds__(256) void k_conv(const float* __restrict__ A,
                                              u16* __restrict__ Ab,
                                              const float* __restrict__ W,
                                              const float* __restrict__ av,
                                              float* __restrict__ Wa) {
  if (blockIdx.x == 8192) {          // Wa[k][h] = sum_u W[k][h*64+u]*av[64+u]
    const int k = threadIdx.x;       // 0..255
    const float* wr = W + (size_t)k * 512;
#pragma unroll
    for (int h = 0; h < 8; ++h) {
      float s = 0.f;
      for (int u = 0; u < 64; ++u) s += wr[h * 64 + u] * av[64 + u];
      Wa[k * 8 + h] = s;
    }
    return;
  }
  size_t i = ((size_t)blockIdx.x * 256 + threadIdx.x) * 8;
  float4 a0 = *(const float4*)(A + i);
  float4 a1 = *(const float4*)(A + i + 4);
  uint4 o;
  o.x = (u32)f2bf(a0.x) | ((u32)f2bf(a0.y) << 16);
  o.y = (u32)f2bf(a0.z) | ((u32)f2bf(a0.w) << 16);
  o.z = (u32)f2bf(a1.x) | ((u32)f2bf(a1.y) << 16);
  o.w = (u32)f2bf(a1.z) | ((u32)f2bf(a1.w) << 16);
  *(uint4*)(Ab + i) = o;
}

// ---------------------------------------------------------------------------
// Kernel 2: fused X@W (fp32) + e_dst + exp + scaled bf16 transposed store.
// Block: 16 j-rows x 128 c-cols. Grid (256, 4) = 1024 blocks = 4/CU.
// ---------------------------------------------------------------------------
__global__ __launch_bounds__(256) void k_hg(const float* __restrict__ X,
                                            const float* __restrict__ W,
                                            const float* __restrict__ Wa,
                                            u16* __restrict__ Gt) {
  __shared__ float xs[256 * 20];       // xs[k*20 + jj], pad 20 keeps 16B align
  __shared__ float WaL[256 * 8];
  __shared__ float edp[16 * 8 * 2];
  __shared__ float w8L[16 * 8];
  const int t  = threadIdx.x;
  const int j0 = blockIdx.x * 16;
  const int c0 = blockIdx.y * 128;

  // stage X tile transposed: xs[k][jj]
  {
    const int jj = t >> 4, seg = t & 15;
    const float* src = X + (size_t)(j0 + jj) * 256 + seg * 16;
#pragma unroll
    for (int q = 0; q < 16; q += 4) {
      float4 v = *(const float4*)(src + q);
      xs[(seg * 16 + q + 0) * 20 + jj] = v.x;
      xs[(seg * 16 + q + 1) * 20 + jj] = v.y;
      xs[(seg * 16 + q + 2) * 20 + jj] = v.z;
      xs[(seg * 16 + q + 3) * 20 + jj] = v.w;
    }
    *(float4*)&WaL[t * 8]     = *(const float4*)(Wa + t * 8);
    *(float4*)&WaL[t * 8 + 4] = *(const float4*)(Wa + t * 8 + 4);
  }
  __syncthreads();

  // e_dst partials: thread = (jj, h, half)
  {
    const int jj = t >> 4, h = (t & 15) >> 1, half = t & 1;
    float e = 0.f;
    for (int ki = 0; ki < 128; ++ki) {
      int k = half * 128 + ki;
      e += xs[k * 20 + jj] * WaL[k * 8 + h];
    }
    edp[(jj * 8 + h) * 2 + half] = e;
  }
  __syncthreads();
  if (t < 128) {
    const int jj = t >> 3, h = t & 7;
    float e = edp[(jj * 8 + h) * 2] + edp[(jj * 8 + h) * 2 + 1];
    e = fminf(30.f, fmaxf(-30.f, e));
    float w = __expf(e);
    w8L[jj * 8 + h] = w;
    if (c0 == 0) Gt[(size_t)(512 + h) * 4096 + j0 + jj] = f2bf(w);  // den rows
  }
  if (c0 == 0 && t < 120) {            // zero pad rows 520..639 for this j-slice
    const int c = 520 + t;
    uint4 z4 = {0u, 0u, 0u, 0u};
    *(uint4*)(Gt + (size_t)c * 4096 + j0)     = z4;
    *(uint4*)(Gt + (size_t)c * 4096 + j0 + 8) = z4;
  }
  __syncthreads();

  // main: thread owns col c, 8 j-rows (jg half)
  const int c  = c0 + (t & 127);
  const int jg = t >> 7;
  float acc[8];
#pragma unroll
  for (int r = 0; r < 8; ++r) acc[r] = 0.f;
  const float* wp = W + c;
#pragma unroll 4
  for (int k = 0; k < 256; ++k) {
    float  w0 = wp[(size_t)k * 512];
    float4 xa = *(const float4*)&xs[k * 20 + jg * 8];      // broadcast reads
    float4 xb = *(const float4*)&xs[k * 20 + jg * 8 + 4];
    acc[0] += xa.x * w0; acc[1] += xa.y * w0;
    acc[2] += xa.z * w0; acc[3] += xa.w * w0;
    acc[4] += xb.x * w0; acc[5] += xb.y * w0;
    acc[6] += xb.z * w0; acc[7] += xb.w * w0;
  }

  const int h = c >> 6;
  u16x8 o;
#pragma unroll
  for (int jj = 0; jj < 8; ++jj)
    o[jj] = f2bf(acc[jj] * w8L[(jg * 8 + jj) * 8 + h]);
  *(u16x8*)(Gt + (size_t)c * 4096 + j0 + jg * 8) = o;      // 16B store
}

// ---------------------------------------------------------------------------
// Kernel 3: C = Ab(4096x4096) x Gt^T -> P[z] (split-K partials, fp32)
// 128x128 tile, BK=32, global_load_lds w16 with XOR chunk swizzle.
// ---------------------------------------------------------------------------
__global__ __launch_bounds__(256) void k_gemm(const u16* __restrict__ Ab,
                                              const u16* __restrict__ Gt,
                                              float* __restrict__ P,
                                              int kslice) {
  __shared__ __align__(16) u16 lA[128 * 32];
  __shared__ __align__(16) u16 lB[128 * 32];
  const int t    = threadIdx.x;
  const int n0   = blockIdx.x * 128;
  const int i0   = blockIdx.y * 128;
  const int kt0  = blockIdx.z * kslice;
  const int w    = t >> 6, lane = t & 63;
  const int wr   = w >> 1, wc = w & 1;
  const int quad = lane >> 4, l15 = lane & 15;

  floatx4 acc[4][4];
  const floatx4 zz = {0.f, 0.f, 0.f, 0.f};
#pragma unroll
  for (int mt = 0; mt < 4; ++mt)
#pragma unroll
    for (int nt = 0; nt < 4; ++nt) acc[mt][nt] = zz;

  // staging with XOR swizzle: LDS slot (r, cl) holds global k-chunk cl^(r&3).
  // Lane->LDS dest is fixed (base + lane*16); we permute the global source.
  const int r0 = t >> 2;
  const int cs = (t & 3) ^ (r0 & 3);           // swizzled k-chunk (16B units)
  const int r1 = 64 + r0;                      // r1&3 == r0&3
  const u16* pa0 = Ab + (size_t)(i0 + r0) * 4096 + kt0 + cs * 8;
  const u16* pa1 = Ab + (size_t)(i0 + r1) * 4096 + kt0 + cs * 8;
  const u16* pb0 = Gt + (size_t)(n0 + r0) * 4096 + kt0 + cs * 8;
  const u16* pb1 = Gt + (size_t)(n0 + r1) * 4096 + kt0 + cs * 8;
  const int wbase = (t & 192) * 8;
  u16* la0 = &lA[wbase];
  u16* la1 = &lA[2048 + wbase];
  u16* lb0 = &lB[wbase];
  u16* lb1 = &lB[2048 + wbase];

  const int sw = (quad ^ (l15 & 3)) * 8;       // frag-read chunk de-swizzle

  for (int kk = 0; kk < kslice; kk += 32) {
    async_ld16(pa0 + kk, la0);
    async_ld16(pa1 + kk, la1);
    async_ld16(pb0 + kk, lb0);
    async_ld16(pb1 + kk, lb1);
    __syncthreads();

    short8 af[4], bf[4];
#pragma unroll
    for (int mt = 0; mt < 4; ++mt)
      af[mt] = *(const short8*)&lA[(wr * 64 + mt * 16 + l15) * 32 + sw];
#pragma unroll
    for (int nt = 0; nt < 4; ++nt)
      bf[nt] = *(const short8*)&lB[(wc * 64 + nt * 16 + l15) * 32 + sw];
#pragma unroll
    for (int mt = 0; mt < 4; ++mt)
#pragma unroll
      for (int nt = 0; nt < 4; ++nt)
        acc[mt][nt] = __builtin_amdgcn_mfma_f32_16x16x32_bf16(af[mt], bf[nt],
                                                              acc[mt][nt], 0, 0, 0);
    __syncthreads();
  }

  // epilogue: C/D layout col = lane&15, row = quad*4 + reg
  float* Pp = P + (size_t)blockIdx.z * 2621440;   // 4096*640
#pragma unroll
  for (int mt = 0; mt < 4; ++mt) {
#pragma unroll
    for (int r = 0; r < 4; ++r) {
      int i = i0 + wr * 64 + mt * 16 + quad * 4 + r;
      float* row = Pp + (size_t)i * 640 + n0 + wc * 64 + l15;
#pragma unroll
      for (int nt = 0; nt < 4; ++nt) row[nt * 16] = acc[mt][nt][r];
    }
  }
}

// ---------------------------------------------------------------------------
// Kernel 4: out[i, u*8+h] = relu( sum_z num / sum_z den )
// ---------------------------------------------------------------------------
__global__ __launch_bounds__(256) void k_out(const float* __restrict__ P,
                                             float* __restrict__ out, int Z) {
  __shared__ float ps[640];
  const int t = threadIdx.x;
  const int i = blockIdx.x;
  for (int q = t; q < 640; q += 256) {
    float s = 0.f;
    for (int z = 0; z < Z; ++z)
      s += P[(size_t)z * 2621440 + (size_t)i * 640 + q];
    ps[q] = s;
  }
  __syncthreads();
  for (int c = t; c < 512; c += 256) {
    int u = c >> 3, hd = c & 7;
    float o = ps[hd * 64 + u] / ps[512 + hd];
    out[(size_t)i * 512 + c] = fmaxf(o, 0.f);
  }
}

extern "C" void kernel_launch(void* const* d_in, const int* in_sizes, int n_in,
                              void* d_out, int out_size, void* d_ws, size_t ws_size,
                              hipStream_t stream) {
  const float* X  = (const float*)d_in[0];
  const float* A  = (const float*)d_in[1];
  const float* W  = (const float*)d_in[2];
  const float* av = (const float*)d_in[3];
  float* out = (float*)d_out;
  char*  ws  = (char*)d_ws;

  u16*   Ab = (u16*)(ws + 0);
  u16*   Gt = (u16*)(ws + 33554432);
  float* Wa = (float*)(ws + 38797312);
  float* P  = (float*)(ws + 38805504);

  const size_t pz = 10485760ull;                       // bytes per split-K slice
  const int Z = (ws_size >= 38805504ull + 8 * pz) ? 8 : 4;
  const int kslice = 4096 / Z;

  k_conv<<<8193, 256, 0, stream>>>(A, Ab, W, av, Wa);
  k_hg<<<dim3(256, 4), 256, 0, stream>>>(X, W, Wa, Gt);
  k_gemm<<<dim3(5, 32, Z), 256, 0, stream>>>(Ab, Gt, P, kslice);
  k_out<<<4096, 256, 0, stream>>>(P, out, Z);
}

// Round 4
// 190.185 us; speedup vs baseline: 1.2261x; 1.1961x over previous
//
#include <hip/hip_runtime.h>

// GraphAttentionLayer: B=1, N=4096, F=256, H=8, U=64
//
// e_src cancels in softmax over j =>
//   out[i, u*8+h] = relu( (A @ (w*h))[i, h*64+u] / (A @ w)[i, h] ),  w = exp(e_dst)
// => ONE dense GEMM  C = A(4096x4096) x G(4096x544), G = [w*h (512) | w (8) | 0 (24)]
//
// R4 = R3 with two fixes:
//  - k_out: restore the (u,h) permutation (R3 wrote out[c] = P[c] — the bug)
//  - k_hg : pad-zeroing covered only even slots; now covers all 48 pad slots
//
// Structure:
//  - k_hg  : fp32 X@W, dbuf LDS tiles, fused e_dst/exp; writes G in the exact
//            32x32x16-bf16 B-FRAGMENT layout (Gtp) so gemm B-loads are
//            lane-contiguous global_load_dwordx4 (no LDS for B).
//  - k_gemm: M=32-row blocks x full N=544, Z=4 split-K. A (fp32, {0,1}) is
//            streamed from HBM exactly once, converted to bf16 in-kernel.
//            B re-read from L2 (4.4 MB hot). atomicAdd into single P.
//  - k_out : num/den + relu + (u,h) permute.
//
// Gtp layout: tile (tk = k>>4, nt = n>>5), tile id = tk*17+nt, 1024 B each:
//   u16[ tileid*512 + ((n&31) + 32*((k&15)>>3))*8 + (k&7) ]
// so B-frag(lane) = 16 B at tileid*1024 + lane*16  (B[k][n]: n=lane&31, k=(lane>>5)*8+j)
//
// ws: P @0 (4096*544*4 = 8,912,896 B) | Gtp @8912896 (4352*1024 = 4,456,448 B)

typedef unsigned short u16;
typedef unsigned int   u32;
typedef __attribute__((ext_vector_type(8)))  short  short8;    // 8 bf16 (4 VGPR)
typedef __attribute__((ext_vector_type(16))) float  floatx16;  // 32x32 MFMA acc
typedef __attribute__((ext_vector_type(8)))  unsigned short u16x8;
typedef __attribute__((ext_vector_type(4)))  unsigned short u16x4;

__device__ __forceinline__ u16 f2bf(float x) {
  u32 u = __float_as_uint(x);
  u += 0x7fffu + ((u >> 16) & 1u);   // RNE
  return (u16)(u >> 16);
}

__device__ __forceinline__ void async_ld16(const void* g, void* l) {
  __builtin_amdgcn_global_load_lds((const __attribute__((address_space(1))) void*)g,
                                   (__attribute__((address_space(3))) void*)l,
                                   16, 0, 0);
}

// ---------------------------------------------------------------------------
// Kernel 1: h = X@W (fp32, exact), e_dst -> w = exp, write Gtp (B-frag layout).
// Block: 64 j-rows x 128 c-cols (= 2 full heads, so e-sums are block-local).
// Thread: 8 j x 4 c. K in 4 chunks of 64, double-buffered; W via async
// global_load_lds, X transposed via regs. Grid (64, 4) = 256 blocks.
// ---------------------------------------------------------------------------
__global__ __launch_bounds__(256) void k_hg(const float* __restrict__ X,
                                            const float* __restrict__ W,
                                            const float* __restrict__ av,
                                            u16* __restrict__ Gtp) {
  __shared__ __align__(16) float Wc[2][64 * 128];  // 64 KB
  __shared__ __align__(16) float xs[2][64 * 64];   // 32 KB  xs[k][j]
  __shared__ float eL[64 * 2];
  __shared__ float w8L[64 * 2];
  const int t  = threadIdx.x;
  const int j0 = blockIdx.x * 64;
  const int y  = blockIdx.y;          // head pair: heads 2y, 2y+1
  const int c0 = y * 128;

  const int cq = t & 31;              // c = c0 + cq*4 + cv
  const int tj = t >> 5;              // j = j0 + tj*8 + jv

  if (t < 128) eL[t] = 0.f;

  const int xjj = t >> 2, xf = t & 3; // X stage: row j0+xjj, floats [xf*16, xf*16+16)
  float xreg[16];

  // ---- prologue: stage chunk 0 ----
#pragma unroll
  for (int l = 0; l < 8; ++l) {       // W chunk 0 -> Wc[0] (async, lane-contig dest)
    int id = l * 256 + t;
    int kk = id >> 5, ch = id & 31;
    async_ld16(W + (size_t)kk * 512 + c0 + ch * 4,
               (char*)&Wc[0][0] + (size_t)(l * 256 + (t & 192)) * 16);
  }
  {
    const float* xp = X + (size_t)(j0 + xjj) * 256 + xf * 16;
#pragma unroll
    for (int q = 0; q < 4; ++q) {
      float4 v = *(const float4*)(xp + q * 4);
      xreg[4 * q] = v.x; xreg[4 * q + 1] = v.y; xreg[4 * q + 2] = v.z; xreg[4 * q + 3] = v.w;
    }
#pragma unroll
    for (int e = 0; e < 16; ++e) xs[0][(xf * 16 + e) * 64 + xjj] = xreg[e];
  }

  float acc[8][4];
#pragma unroll
  for (int jv = 0; jv < 8; ++jv)
#pragma unroll
    for (int cv = 0; cv < 4; ++cv) acc[jv][cv] = 0.f;

  // ---- K loop: 4 chunks of 64, double-buffered ----
  for (int c = 0; c < 4; ++c) {
    __syncthreads();                  // chunk c fully staged (drains async + lds writes)
    const int cb = c & 1, nb = cb ^ 1;
    if (c < 3) {
#pragma unroll
      for (int l = 0; l < 8; ++l) {   // async W chunk c+1 -> other buffer
        int id = l * 256 + t;
        int kk = id >> 5, ch = id & 31;
        async_ld16(W + (size_t)((c + 1) * 64 + kk) * 512 + c0 + ch * 4,
                   (char*)&Wc[nb][0] + (size_t)(l * 256 + (t & 192)) * 16);
      }
      const float* xp = X + (size_t)(j0 + xjj) * 256 + (c + 1) * 64 + xf * 16;
#pragma unroll
      for (int q = 0; q < 4; ++q) {
        float4 v = *(const float4*)(xp + q * 4);
        xreg[4 * q] = v.x; xreg[4 * q + 1] = v.y; xreg[4 * q + 2] = v.z; xreg[4 * q + 3] = v.w;
      }
    }
    const float* Wb = &Wc[cb][0];
    const float* Xb = &xs[cb][0];
#pragma unroll 4
    for (int kk = 0; kk < 64; ++kk) {
      float4 w4 = *(const float4*)(Wb + kk * 128 + cq * 4);
      float4 xa = *(const float4*)(Xb + kk * 64 + tj * 8);      // broadcast
      float4 xb = *(const float4*)(Xb + kk * 64 + tj * 8 + 4);  // broadcast
      acc[0][0] += xa.x * w4.x; acc[0][1] += xa.x * w4.y; acc[0][2] += xa.x * w4.z; acc[0][3] += xa.x * w4.w;
      acc[1][0] += xa.y * w4.x; acc[1][1] += xa.y * w4.y; acc[1][2] += xa.y * w4.z; acc[1][3] += xa.y * w4.w;
      acc[2][0] += xa.z * w4.x; acc[2][1] += xa.z * w4.y; acc[2][2] += xa.z * w4.z; acc[2][3] += xa.z * w4.w;
      acc[3][0] += xa.w * w4.x; acc[3][1] += xa.w * w4.y; acc[3][2] += xa.w * w4.z; acc[3][3] += xa.w * w4.w;
      acc[4][0] += xb.x * w4.x; acc[4][1] += xb.x * w4.y; acc[4][2] += xb.x * w4.z; acc[4][3] += xb.x * w4.w;
      acc[5][0] += xb.y * w4.x; acc[5][1] += xb.y * w4.y; acc[5][2] += xb.y * w4.z; acc[5][3] += xb.y * w4.w;
      acc[6][0] += xb.z * w4.x; acc[6][1] += xb.z * w4.y; acc[6][2] += xb.z * w4.z; acc[6][3] += xb.z * w4.w;
      acc[7][0] += xb.w * w4.x; acc[7][1] += xb.w * w4.y; acc[7][2] += xb.w * w4.z; acc[7][3] += xb.w * w4.w;
    }
    if (c < 3) {                      // transpose-write X chunk c+1 into other buffer
#pragma unroll
      for (int e = 0; e < 16; ++e) xs[nb][(xf * 16 + e) * 64 + xjj] = xreg[e];
    }
  }

  // ---- e_dst = sum_c h[j][c]*a_dst[c&63] (block-local: 2 whole heads) ----
  const int lh = cq >> 4;             // local head (0/1)
  {
    const float* adp = av + 64 + (cq & 15) * 4;
    float ad0 = adp[0], ad1 = adp[1], ad2 = adp[2], ad3 = adp[3];
#pragma unroll
    for (int jv = 0; jv < 8; ++jv) {
      float ep = acc[jv][0] * ad0 + acc[jv][1] * ad1 + acc[jv][2] * ad2 + acc[jv][3] * ad3;
      atomicAdd(&eL[(tj * 8 + jv) * 2 + lh], ep);
    }
  }
  __syncthreads();
  if (t < 128) {
    float e = eL[t];
    e = fminf(30.f, fmaxf(-30.f, e));
    w8L[t] = __expf(e);
  }
  __syncthreads();

  // ---- scaled bf16 stores in B-frag layout ----
  const int tkb = (j0 >> 4) + (tj >> 1);   // k>>4 (uniform per thread)
  const int khh = tj & 1;                  // (k&15)>>3
#pragma unroll
  for (int cv = 0; cv < 4; ++cv) {
    int n  = c0 + cq * 4 + cv;
    int nt = n >> 5;
    u16x8 o;
#pragma unroll
    for (int jv = 0; jv < 8; ++jv)          // k&7 == jv
      o[jv] = f2bf(acc[jv][cv] * w8L[(tj * 8 + jv) * 2 + lh]);
    *(u16x8*)(Gtp + (size_t)(tkb * 17 + nt) * 512 + ((n & 31) + 32 * khh) * 8) = o;
  }
  // den rows (n = 512 + h): slots h (khh=0) and 32+h (khh=1) of tile nt=16
  if (t < 128) {
    int jj = t >> 1, lh2 = t & 1, h = y * 2 + lh2, k = j0 + jj;
    Gtp[(size_t)((k >> 4) * 17 + 16) * 512 + (h + 32 * ((jj & 15) >> 3)) * 8 + (jj & 7)] =
        f2bf(w8L[t]);
  }
  // zero pad (n in [520,544)): slots [8,32) and [40,64) of tile nt=16; y==3 does it
  if (y == 3 && t < 192) {
    int tk2 = t / 48, r = t - tk2 * 48;           // 4 k-tiles, 48 slots each
    int slot = (r < 24) ? (8 + r) : (40 + (r - 24));
    u16x8 z = {0, 0, 0, 0, 0, 0, 0, 0};
    *(u16x8*)(Gtp + (size_t)(((j0 >> 4) + tk2) * 17 + 16) * 512 + slot * 8) = z;
  }
}

// ---------------------------------------------------------------------------
// Kernel 2: C += A(fp32,{0,1}) x G^T via 32x32x16 bf16 MFMA, atomicAdd into P.
// Block: M=32 x N=544 (17 tiles; wave w owns tiles w,w+4,...), K-slice 1024.
// A: fp32->bf16 in-kernel, swizzled LDS (only A uses LDS; 4-wave reuse).
// B: direct global_load_dwordx4 from Gtp (lane-contiguous, L2-hot).
// Grid (128, Z=4) = 512 blocks = 2/CU.
// ---------------------------------------------------------------------------
__global__ __launch_bounds__(256, 2) void k_gemm(const float* __restrict__ A,
                                                 const u16* __restrict__ Gtp,
                                                 float* __restrict__ P) {
  __shared__ __align__(16) u16 As[32 * 32];
  const int t    = threadIdx.x;
  const int i0   = blockIdx.x * 32;
  const int kt0  = blockIdx.y * 1024;
  const int w    = t >> 6, lane = t & 63;
  const int ml   = lane & 31, kh = lane >> 5;

  floatx16 acc[5];
#pragma unroll
  for (int q = 0; q < 5; ++q)
#pragma unroll
    for (int r = 0; r < 16; ++r) acc[q][r] = 0.f;

  // A staging: thread -> row ar, 4 k's at ak; XOR chunk swizzle vs row
  const int ar  = t >> 3;
  const int ak  = (t & 7) * 4;
  const int alc = ak >> 3;
  const float* pa = A + (size_t)(i0 + ar) * 4096 + kt0 + ak;
  u16* asw = As + ar * 32 + ((alc ^ ((ar >> 1) & 3)) * 8) + (ak & 7);

  // A-frag read offsets (u16): lane m=ml, k-half kh; de-swizzle chunk
  const int aoff0 = ml * 32 + ((kh ^ ((ml >> 1) & 3)) * 8);        // kstep 0
  const int aoff1 = ml * 32 + (((2 + kh) ^ ((ml >> 1) & 3)) * 8);  // kstep 1

  int ntv[5];
#pragma unroll
  for (int q = 0; q < 5; ++q) ntv[q] = w + q * 4;   // valid if < 17

  float4 a4 = *(const float4*)pa;                    // prefetch kk=0
  for (int kk = 0; kk < 1024; kk += 32) {
    // B frags: lane-contiguous 16 B loads from L2-hot Gtp
    short8 bq[5][2];
    const int ktile = (kt0 + kk) >> 4;
#pragma unroll
    for (int q = 0; q < 5; ++q)
      if (ntv[q] < 17)
#pragma unroll
        for (int s = 0; s < 2; ++s)
          bq[q][s] = *(const short8*)(Gtp + (size_t)((ktile + s) * 17 + ntv[q]) * 512 + lane * 8);

    __syncthreads();                 // prior iter's As reads done
    u16x4 ab = {f2bf(a4.x), f2bf(a4.y), f2bf(a4.z), f2bf(a4.w)};
    *(u16x4*)asw = ab;
    if (kk + 32 < 1024) a4 = *(const float4*)(pa + kk + 32);   // prefetch next
    __syncthreads();                 // As staged

    short8 a0 = *(const short8*)(As + aoff0);
    short8 a1 = *(const short8*)(As + aoff1);
#pragma unroll
    for (int q = 0; q < 5; ++q)
      if (ntv[q] < 17) {
        acc[q] = __builtin_amdgcn_mfma_f32_32x32x16_bf16(a0, bq[q][0], acc[q], 0, 0, 0);
        acc[q] = __builtin_amdgcn_mfma_f32_32x32x16_bf16(a1, bq[q][1], acc[q], 0, 0, 0);
      }
  }

  // epilogue: C/D layout col=lane&31, row=(r&3)+8*(r>>2)+4*(lane>>5); atomic acc
  const int rbase = i0 + 4 * kh;
#pragma unroll
  for (int q = 0; q < 5; ++q)
    if (ntv[q] < 17) {
      int n = ntv[q] * 32 + ml;
      if (n < 520) {
#pragma unroll
        for (int r = 0; r < 16; ++r) {
          int row = rbase + (r & 3) + 8 * (r >> 2);
          atomicAdd(P + (size_t)row * 544 + n, acc[q][r]);
        }
      }
    }
}

// ---------------------------------------------------------------------------
// Kernel 3: out[i, u*8+h] = relu( P[i][h*64+u] / P[i][512+h] ).
// 2 rows per block via LDS stage (the R3 bug was skipping this permute).
// ---------------------------------------------------------------------------
__global__ __launch_bounds__(256) void k_out(const float* __restrict__ P,
                                             float* __restrict__ out) {
  __shared__ float ps[2][544];
  const int t    = threadIdx.x;
  const int half = t >> 7, lt = t & 127;
  const int i    = blockIdx.x * 2 + half;
  const float* pr = P + (size_t)i * 544;
  for (int q = lt; q < 544; q += 128) ps[half][q] = pr[q];
  __syncthreads();
  for (int c = lt; c < 512; c += 128) {           // c = u*8 + h
    int u = c >> 3, hd = c & 7;
    float o = ps[half][hd * 64 + u] / ps[half][512 + hd];
    out[(size_t)i * 512 + c] = fmaxf(o, 0.f);
  }
}

extern "C" void kernel_launch(void* const* d_in, const int* in_sizes, int n_in,
                              void* d_out, int out_size, void* d_ws, size_t ws_size,
                              hipStream_t stream) {
  const float* X  = (const float*)d_in[0];
  const float* A  = (const float*)d_in[1];
  const float* W  = (const float*)d_in[2];
  const float* av = (const float*)d_in[3];
  float* out = (float*)d_out;
  char*  ws  = (char*)d_ws;

  float* P   = (float*)ws;                 // 4096*544*4
  u16*   Gtp = (u16*)(ws + 8912896);       // 256*17 tiles * 1024 B

  hipMemsetAsync(P, 0, 8912896, stream);
  k_hg<<<dim3(64, 4), 256, 0, stream>>>(X, W, av, Gtp);
  k_gemm<<<dim3(128, 4), 256, 0, stream>>>(A, Gtp, P);
  k_out<<<2048, 256, 0, stream>>>(P, out);
}

// Round 5
// 173.171 us; speedup vs baseline: 1.3466x; 1.0983x over previous
//
#include <hip/hip_runtime.h>

// GraphAttentionLayer: B=1, N=4096, F=256, H=8, U=64
//
// e_src cancels in softmax over j =>
//   out[i, u*8+h] = relu( (A @ (w*h))[i, h*64+u] / (A @ w)[i, h] ),  w = exp(e_dst)
// => ONE dense GEMM  C = A(4096x4096) x G(4096x544), G = [w*h (512) | w (8) | 0 (24)]
//
// R5: barrier-amortized gemm (K=256 LDS chunks, 7 barriers/block instead of 64;
// R4 drained vmcnt(0) at 2 barriers per K=32 -> latency-bound at 75 us),
// M=64 512-thread blocks, branchless tile clamp; k_hg re-gridded to 2 blk/CU
// and absorbs the P-memset (3 dispatches total).
//
// Gtp layout (HW-verified R4): tile (tk=k>>4, nt=n>>5), id=tk*17+nt, 1024 B:
//   u16[ id*512 + ((n&31) + 32*((k&15)>>3))*8 + (k&7) ]
// B-frag(lane) = 16 B at id*1024 + lane*16.
//
// ws: P @0 (4096*544*4 = 8,912,896 B) | Gtp @8912896 (4352 tiles * 1024 B)

typedef unsigned short u16;
typedef unsigned int   u32;
typedef __attribute__((ext_vector_type(8)))  short  short8;    // 8 bf16 (4 VGPR)
typedef __attribute__((ext_vector_type(16))) float  floatx16;  // 32x32 MFMA acc
typedef __attribute__((ext_vector_type(8)))  unsigned short u16x8;
typedef __attribute__((ext_vector_type(4)))  unsigned short u16x4;

__device__ __forceinline__ u16 f2bf(float x) {
  u32 u = __float_as_uint(x);
  u += 0x7fffu + ((u >> 16) & 1u);   // RNE
  return (u16)(u >> 16);
}

__device__ __forceinline__ void async_ld16(const void* g, void* l) {
  __builtin_amdgcn_global_load_lds((const __attribute__((address_space(1))) void*)g,
                                   (__attribute__((address_space(3))) void*)l,
                                   16, 0, 0);
}

// ---------------------------------------------------------------------------
// Kernel 1: h = X@W (fp32, exact), e_dst -> w = exp, write Gtp (B-frag layout).
// Block: 32 j-rows x 128 c-cols (2 whole heads => e-sums block-local).
// Thread: 4j x 4c. K in 4 single-buffered chunks of 64 (W async->LDS, X
// transposed). Grid (128, 4) = 512 blocks = 2/CU. Also zeroes P.
// ---------------------------------------------------------------------------
__global__ __launch_bounds__(256) void k_hg(const float* __restrict__ X,
                                            const float* __restrict__ W,
                                            const float* __restrict__ av,
                                            u16* __restrict__ Gtp,
                                            float* __restrict__ P) {
  __shared__ __align__(16) float Wc[64 * 128];   // 32 KB
  __shared__ __align__(16) float xs[64 * 36];    // 9 KB (pad 36 breaks stride)
  __shared__ float eL[64];
  __shared__ float w8L[64];
  const int t  = threadIdx.x;
  const int j0 = blockIdx.x * 32;
  const int y  = blockIdx.y;           // heads 2y, 2y+1
  const int c0 = y * 128;
  const int cq = t & 31, tj = t >> 5;

  // zero this block's P slab (557,056 float4 / 512 blocks = 1088 each)
  {
    float4* P4 = (float4*)P;
    const int base = ((int)blockIdx.y * 128 + (int)blockIdx.x) * 1088;
    float4 z = {0.f, 0.f, 0.f, 0.f};
#pragma unroll
    for (int q = 0; q < 4; ++q) P4[base + q * 256 + t] = z;
    if (t < 64) P4[base + 1024 + t] = z;
  }
  if (t < 64) eL[t] = 0.f;

  float acc[4][4];
#pragma unroll
  for (int a = 0; a < 4; ++a)
#pragma unroll
    for (int b = 0; b < 4; ++b) acc[a][b] = 0.f;

  const int xjj = t >> 3, xoff = (t & 7) * 8;

  for (int cc = 0; cc < 4; ++cc) {
    // stage W chunk (64 k x 128 c) via async global->LDS
#pragma unroll
    for (int l = 0; l < 8; ++l) {
      int id = l * 256 + t;
      int kk = id >> 5, ch = id & 31;
      async_ld16(W + (size_t)(cc * 64 + kk) * 512 + c0 + ch * 4,
                 (char*)&Wc[0] + (size_t)(l * 256 + (t & 192)) * 16);
    }
    // stage X chunk transposed: xs[k][j]
    {
      const float* xp = X + (size_t)(j0 + xjj) * 256 + cc * 64 + xoff;
      float4 v0 = *(const float4*)xp;
      float4 v1 = *(const float4*)(xp + 4);
      xs[(xoff + 0) * 36 + xjj] = v0.x; xs[(xoff + 1) * 36 + xjj] = v0.y;
      xs[(xoff + 2) * 36 + xjj] = v0.z; xs[(xoff + 3) * 36 + xjj] = v0.w;
      xs[(xoff + 4) * 36 + xjj] = v1.x; xs[(xoff + 5) * 36 + xjj] = v1.y;
      xs[(xoff + 6) * 36 + xjj] = v1.z; xs[(xoff + 7) * 36 + xjj] = v1.w;
    }
    __syncthreads();
#pragma unroll 4
    for (int kk = 0; kk < 64; ++kk) {
      float4 w4 = *(const float4*)(&Wc[kk * 128 + cq * 4]);
      float4 xa = *(const float4*)(&xs[kk * 36 + tj * 4]);   // broadcast
      acc[0][0] += xa.x * w4.x; acc[0][1] += xa.x * w4.y; acc[0][2] += xa.x * w4.z; acc[0][3] += xa.x * w4.w;
      acc[1][0] += xa.y * w4.x; acc[1][1] += xa.y * w4.y; acc[1][2] += xa.y * w4.z; acc[1][3] += xa.y * w4.w;
      acc[2][0] += xa.z * w4.x; acc[2][1] += xa.z * w4.y; acc[2][2] += xa.z * w4.z; acc[2][3] += xa.z * w4.w;
      acc[3][0] += xa.w * w4.x; acc[3][1] += xa.w * w4.y; acc[3][2] += xa.w * w4.z; acc[3][3] += xa.w * w4.w;
    }
    __syncthreads();
  }

  // e_dst partials (2 block-local heads)
  const int lh = cq >> 4;
  {
    const float4 ad = *(const float4*)(av + 64 + (cq & 15) * 4);
#pragma unroll
    for (int jv = 0; jv < 4; ++jv) {
      float ep = acc[jv][0] * ad.x + acc[jv][1] * ad.y + acc[jv][2] * ad.z + acc[jv][3] * ad.w;
      atomicAdd(&eL[(tj * 4 + jv) * 2 + lh], ep);
    }
  }
  __syncthreads();
  if (t < 64) {
    float e = fminf(30.f, fmaxf(-30.f, eL[t]));
    w8L[t] = __expf(e);
  }
  __syncthreads();

  // scaled bf16 stores in B-frag layout
  const int tk  = (j0 >> 4) + (tj >> 2);     // j>>4 for j = j0 + tj*4 + jv
  const int khh = (tj >> 1) & 1;             // (j&15)>>3
  const int jlo = (tj & 1) * 4;              // j&7 base
#pragma unroll
  for (int cv = 0; cv < 4; ++cv) {
    int n  = c0 + cq * 4 + cv;
    int nt = n >> 5;
    u16x4 o;
#pragma unroll
    for (int jv = 0; jv < 4; ++jv)
      o[jv] = f2bf(acc[jv][cv] * w8L[(tj * 4 + jv) * 2 + lh]);
    *(u16x4*)(Gtp + (size_t)(tk * 17 + nt) * 512 + ((n & 31) + 32 * khh) * 8 + jlo) = o;
  }
  // den rows (n = 512 + h, this block's 2 heads x 32 rows)
  if (t < 64) {
    int jj = t >> 1, lh2 = t & 1, h = 2 * y + lh2, j = j0 + jj;
    Gtp[(size_t)((j >> 4) * 17 + 16) * 512 + (h + 32 * ((jj & 15) >> 3)) * 8 + (jj & 7)] =
        f2bf(w8L[jj * 2 + lh2]);
  }
  // zero pad (n in [520,544)): slots [8,32) and [40,64) of tile nt=16; y==3 does it
  if (y == 3 && t < 96) {
    int tk2 = t / 48, r = t - tk2 * 48;
    int slot = (r < 24) ? (8 + r) : (16 + r);
    u16x8 z = {0, 0, 0, 0, 0, 0, 0, 0};
    *(u16x8*)(Gtp + (size_t)(((j0 >> 4) + tk2) * 17 + 16) * 512 + slot * 8) = z;
  }
}

// ---------------------------------------------------------------------------
// Kernel 2: C += A(fp32,{0,1}) x G^T via 32x32x16 bf16 MFMA, atomicAdd into P.
// Block: 512 threads = 8 waves (wr 2 m-strips x wc 4 n-groups), M=64, N=544.
// A: K=256 chunks, fp32->bf16, XOR-swizzled double-buffered LDS (2x32 KB);
// only 7 barriers/block. B: direct dwordx4 from L2-hot Gtp, no barrier in the
// 8-dstep inner loop -> compiler pipelines with fine vmcnt.
// Grid (64, Z=4) = 256 blocks.
// ---------------------------------------------------------------------------
__global__ __launch_bounds__(512, 2) void k_gemm(const float* __restrict__ A,
                                                 const u16* __restrict__ Gtp,
                                                 float* __restrict__ P) {
  __shared__ __align__(16) u16 As[2][64 * 256];  // 2 x 32 KB
  const int t    = threadIdx.x;
  const int i0   = blockIdx.x * 64;
  const int kt0  = blockIdx.y * 1024;
  const int w    = t >> 6, lane = t & 63;
  const int wr   = w >> 2, wc = w & 3;
  const int ml   = lane & 31, kh = lane >> 5;

  floatx16 acc[5];
#pragma unroll
  for (int q = 0; q < 5; ++q)
#pragma unroll
    for (int r = 0; r < 16; ++r) acc[q][r] = 0.f;

  // A staging: thread -> row ar (0..63), q-th float4 at k = (t&7)*4 + q*32
  const int ar  = t >> 3;
  const int af  = (t & 7) * 4;
  const float* pa = A + (size_t)(i0 + ar) * 4096 + kt0 + af;
  const int sbase = ar * 256 + (t & 1) * 4;   // + swizzled chunk*8
  const int scb   = (t & 7) >> 1;             // chunk = q*4 + scb
  const int arx   = ar & 7;

  // A-frag reads: row m = wr*32+ml, chunk c -> physical c^(ml&7)
  const int arow = (wr * 32 + ml) * 256;
  const int mx   = ml & 7;

  int nta[5];
#pragma unroll
  for (int q = 0; q < 5; ++q) { int v = wc + 4 * q; nta[q] = v < 17 ? v : 16; }

  float4 areg[8];
#pragma unroll
  for (int q = 0; q < 8; ++q) areg[q] = *(const float4*)(pa + q * 32);
#pragma unroll
  for (int q = 0; q < 8; ++q) {
    u16x4 v = {f2bf(areg[q].x), f2bf(areg[q].y), f2bf(areg[q].z), f2bf(areg[q].w)};
    *(u16x4*)(&As[0][sbase + ((q * 4 + scb) ^ arx) * 8]) = v;
  }
  __syncthreads();

  for (int cc = 0; cc < 4; ++cc) {
    const int cb = cc & 1;
    if (cc < 3) {                    // prefetch next chunk early (hidden by compute)
#pragma unroll
      for (int q = 0; q < 8; ++q)
        areg[q] = *(const float4*)(pa + (cc + 1) * 256 + q * 32);
    }
    const int ktb = (kt0 >> 4) + cc * 16;
#pragma unroll 2
    for (int ds = 0; ds < 8; ++ds) {
      short8 b0[5], b1[5];
#pragma unroll
      for (int q = 0; q < 5; ++q) {
        b0[q] = *(const short8*)(Gtp + (size_t)((ktb + ds * 2) * 17 + nta[q]) * 512 + lane * 8);
        b1[q] = *(const short8*)(Gtp + (size_t)((ktb + ds * 2 + 1) * 17 + nta[q]) * 512 + lane * 8);
      }
      short8 a0 = *(const short8*)(&As[cb][arow + ((ds * 4 + kh) ^ mx) * 8]);
      short8 a1 = *(const short8*)(&As[cb][arow + ((ds * 4 + 2 + kh) ^ mx) * 8]);
#pragma unroll
      for (int q = 0; q < 5; ++q)
        acc[q] = __builtin_amdgcn_mfma_f32_32x32x16_bf16(a0, b0[q], acc[q], 0, 0, 0);
#pragma unroll
      for (int q = 0; q < 5; ++q)
        acc[q] = __builtin_amdgcn_mfma_f32_32x32x16_bf16(a1, b1[q], acc[q], 0, 0, 0);
    }
    if (cc < 3) {
      __syncthreads();               // readers of other buffer done
#pragma unroll
      for (int q = 0; q < 8; ++q) {
        u16x4 v = {f2bf(areg[q].x), f2bf(areg[q].y), f2bf(areg[q].z), f2bf(areg[q].w)};
        *(u16x4*)(&As[cb ^ 1][sbase + ((q * 4 + scb) ^ arx) * 8]) = v;
      }
      __syncthreads();               // writes visible
    }
  }

  // epilogue: C/D layout col=lane&31, row=(r&3)+8*(r>>2)+4*(lane>>5); atomics
  const int rbase = i0 + wr * 32 + 4 * kh;
#pragma unroll
  for (int q = 0; q < 5; ++q) {
    int n = (wc + 4 * q) * 32 + ml;
    if (n < 520) {
#pragma unroll
      for (int r = 0; r < 16; ++r) {
        int row = rbase + (r & 3) + 8 * (r >> 2);
        atomicAdd(P + (size_t)row * 544 + n, acc[q][r]);
      }
    }
  }
}

// ---------------------------------------------------------------------------
// Kernel 3: out[i, u*8+h] = relu( P[i][h*64+u] / P[i][512+h] ). 2 rows/block.
// ---------------------------------------------------------------------------
__global__ __launch_bounds__(256) void k_out(const float* __restrict__ P,
                                             float* __restrict__ out) {
  __shared__ float ps[2][544];
  const int t    = threadIdx.x;
  const int half = t >> 7, lt = t & 127;
  const int i    = blockIdx.x * 2 + half;
  const float* pr = P + (size_t)i * 544;
  for (int q = lt; q < 544; q += 128) ps[half][q] = pr[q];
  __syncthreads();
  for (int c = lt; c < 512; c += 128) {           // c = u*8 + h
    int u = c >> 3, hd = c & 7;
    float o = ps[half][hd * 64 + u] / ps[half][512 + hd];
    out[(size_t)i * 512 + c] = fmaxf(o, 0.f);
  }
}

extern "C" void kernel_launch(void* const* d_in, const int* in_sizes, int n_in,
                              void* d_out, int out_size, void* d_ws, size_t ws_size,
                              hipStream_t stream) {
  const float* X  = (const float*)d_in[0];
  const float* A  = (const float*)d_in[1];
  const float* W  = (const float*)d_in[2];
  const float* av = (const float*)d_in[3];
  float* out = (float*)d_out;
  char*  ws  = (char*)d_ws;

  float* P   = (float*)ws;                 // 4096*544*4
  u16*   Gtp = (u16*)(ws + 8912896);       // 256*17 tiles * 1024 B

  k_hg<<<dim3(128, 4), 256, 0, stream>>>(X, W, av, Gtp, P);
  k_gemm<<<dim3(64, 4), 512, 0, stream>>>(A, Gtp, P);
  k_out<<<2048, 256, 0, stream>>>(P, out);
}